// Round 18
// baseline (202.510 us; speedup 1.0000x reference)
//
#include <hip/hip_runtime.h>
#include <stdint.h>

#define B_   4
#define S_   2048
#define H_   16
#define DK_  64
#define DM_  1024
#define M_   (B_ * S_)   // 8192

typedef __attribute__((ext_vector_type(4)))  float f32x4;
typedef __attribute__((ext_vector_type(16))) float f32x16;
typedef __attribute__((ext_vector_type(8)))  short s16x8;

#define SCQ 0.18033688011112042f   // (1/sqrt(64)) * log2(e), folded into Q

__device__ __forceinline__ uint16_t f2bf(float f) {
    union { float f; uint32_t u; } v; v.f = f;
    uint32_t u = v.u;
    uint32_t r = (u + 0x7FFFu + ((u >> 16) & 1u)) >> 16;  // RNE
    return (uint16_t)r;
}
__device__ __forceinline__ float bf2f(uint16_t h) {
    union { uint32_t u; float f; } v; v.u = ((uint32_t)h) << 16;
    return v.f;
}
__device__ __forceinline__ uint32_t cvt_pk_bf16(float lo, float hi) {
    uint32_t r;
    asm("v_cvt_pk_bf16_f32 %0, %1, %2" : "=v"(r) : "v"(lo), "v"(hi));
    return r;
}

// async global->LDS, 16B per lane; lds base must be wave-uniform
__device__ __forceinline__ void gload_lds16(const uint16_t* g, uint16_t* l) {
    __builtin_amdgcn_global_load_lds(
        (const __attribute__((address_space(1))) void*)g,
        (__attribute__((address_space(3))) void*)l, 16, 0, 0);
}

// ---------------- fp32 -> bf16 convert, ALL inputs in one launch ----------------
__global__ __launch_bounds__(256) void cvt_all(const float* __restrict__ x,
                                               const float* __restrict__ w0,
                                               const float* __restrict__ w1,
                                               const float* __restrict__ w2,
                                               const float* __restrict__ w3,
                                               uint16_t* __restrict__ xo,
                                               uint16_t* __restrict__ o0,
                                               uint16_t* __restrict__ o1,
                                               uint16_t* __restrict__ o2,
                                               uint16_t* __restrict__ o3) {
    const size_t NX = (size_t)M_ * DM_;
    const size_t NW = (size_t)DM_ * DM_;
    size_t i = ((size_t)blockIdx.x * 256 + threadIdx.x) * 4;
    const float* in; uint16_t* out; size_t off;
    if (i < NX) { in = x; out = xo; off = i; }
    else {
        size_t j = i - NX;
        int sel = (int)(j >> 20);
        off = j & (NW - 1);
        in  = sel == 0 ? w0 : sel == 1 ? w1 : sel == 2 ? w2 : w3;
        out = sel == 0 ? o0 : sel == 1 ? o1 : sel == 2 ? o2 : o3;
    }
    float4 v = *reinterpret_cast<const float4*>(in + off);
    ushort4 o;
    o.x = f2bf(v.x); o.y = f2bf(v.y); o.z = f2bf(v.z); o.w = f2bf(v.w);
    *reinterpret_cast<ushort4*>(out + off) = o;
}

// ---------------- fused QKV projection, dbuf, 32x32x16 MFMA ----------------
// blockIdx.x: sel = x>>3 (0=Q,1=K,2=V), np = x&7 (weight 128-row panel)
// 32x32x16 runs at 2382 TF vs 16x16x32's 2075 (µbench): +21% FLOP/cyc, half the
// MFMA instruction count per K-step. C/D layout: col=lane&31,
// row=(r&3)+8*(r>>2)+4*(lane>>5) (validated by flash's mask since r6).
__global__ __launch_bounds__(256, 4) void gemm_qkv(const uint16_t* __restrict__ xb,
                                                   const uint16_t* __restrict__ wq,
                                                   const uint16_t* __restrict__ wk,
                                                   const uint16_t* __restrict__ wv,
                                                   uint16_t* __restrict__ qout,
                                                   uint16_t* __restrict__ kout,
                                                   uint16_t* __restrict__ vout) {
    __shared__ uint16_t Al[2][128 * 32];
    __shared__ uint16_t Bl[2][128 * 32];
    const int K = DM_;
    const int lane = threadIdx.x & 63;
    const int w    = threadIdx.x >> 6;
    const int wr   = w >> 1, wc = w & 1;
    const int sel  = blockIdx.x >> 3;
    const int np   = blockIdx.x & 7;
    const int y    = blockIdx.y;
    const int ql   = lane & 31;
    const int hi   = lane >> 5;

    const uint16_t* Aptr; const uint16_t* Bptr;
    int m0, n0;
    if (sel == 2) { Aptr = wv; Bptr = xb; m0 = np * 128; n0 = y * 128; }
    else          { Aptr = xb; Bptr = sel ? wk : wq; m0 = y * 128; n0 = np * 128; }

    const int srow = w * 32 + (lane >> 2);
    const int scol = (((lane & 3) ^ ((lane >> 2) & 3))) * 8;   // pre-swizzled chunk
    const uint16_t* Ag = Aptr + (size_t)(m0 + srow) * K + scol;
    const uint16_t* Bg = Bptr + (size_t)(n0 + srow) * K + scol;
    const int loff = w * 32 * 32;   // wave-uniform LDS base (elements)
    const int qsw  = ql & 3;        // read-side XOR key (row&3 == ql&3)

    f32x16 acc[2][2] = {};
    // prologue: stage K-step 0 into buffer 0
#pragma unroll
    for (int i = 0; i < 2; ++i) {
        gload_lds16(Ag + (size_t)i * 16 * K, &Al[0][loff + i * 16 * 32]);
        gload_lds16(Bg + (size_t)i * 16 * K, &Bl[0][loff + i * 16 * 32]);
    }

    int cur = 0;
    for (int k0 = 0; k0 < K; k0 += 32) {
        __syncthreads();   // drains vmcnt: buf[cur] landed; buf[cur^1] reads done
        if (k0 + 32 < K) {
            const int nb = cur ^ 1, k2 = k0 + 32;
#pragma unroll
            for (int i = 0; i < 2; ++i) {
                gload_lds16(Ag + (size_t)i * 16 * K + k2, &Al[nb][loff + i * 16 * 32]);
                gload_lds16(Bg + (size_t)i * 16 * K + k2, &Bl[nb][loff + i * 16 * 32]);
            }
        }
        s16x8 af[2][2], bfr[2][2];
#pragma unroll
        for (int am = 0; am < 2; ++am)
#pragma unroll
            for (int ks = 0; ks < 2; ++ks)
                af[am][ks] = *reinterpret_cast<const s16x8*>(
                    &Al[cur][(wr * 64 + am * 32 + ql) * 32 + (((ks * 2 + hi) ^ qsw) * 8)]);
#pragma unroll
        for (int bn = 0; bn < 2; ++bn)
#pragma unroll
            for (int ks = 0; ks < 2; ++ks)
                bfr[bn][ks] = *reinterpret_cast<const s16x8*>(
                    &Bl[cur][(wc * 64 + bn * 32 + ql) * 32 + (((ks * 2 + hi) ^ qsw) * 8)]);
#pragma unroll
        for (int am = 0; am < 2; ++am)
#pragma unroll
            for (int bn = 0; bn < 2; ++bn) {
                acc[am][bn] = __builtin_amdgcn_mfma_f32_32x32x16_bf16(af[am][0], bfr[bn][0],
                                                                      acc[am][bn], 0, 0, 0);
                acc[am][bn] = __builtin_amdgcn_mfma_f32_32x32x16_bf16(af[am][1], bfr[bn][1],
                                                                      acc[am][bn], 0, 0, 0);
            }
        cur ^= 1;
    }

#pragma unroll
    for (int am = 0; am < 2; ++am)
#pragma unroll
        for (int bn = 0; bn < 2; ++bn)
#pragma unroll
            for (int r = 0; r < 16; ++r) {
                const int cr = (r & 3) + 8 * (r >> 2);
                int row = m0 + wr * 64 + am * 32 + 4 * hi + cr;
                int col = n0 + wc * 64 + bn * 32 + ql;
                float v = acc[am][bn][r];
                if (sel == 2) {   // row over DM (h,dk), col over M (b,s)
                    int h = row >> 6,  dk = row & 63;
                    int b = col >> 11, s = col & (S_ - 1);
                    vout[(((size_t)(b * H_ + h)) * DK_ + dk) * S_ + s] = f2bf(v);
                } else {
                    int b = row >> 11, s = row & (S_ - 1);
                    int h = col >> 6,  dk = col & 63;
                    uint16_t bv = f2bf(sel ? v : v * SCQ);
                    (sel ? kout : qout)[(((size_t)(b * H_ + h)) * S_ + s) * DK_ + dk] = bv;
                }
            }
}

// ---------------- out-projection GEMM, dbuf, 32x32x16: C fp32 = attn * wo^T ----
__global__ __launch_bounds__(256, 4) void gemm_out(const uint16_t* __restrict__ A,
                                                   const uint16_t* __restrict__ Bm,
                                                   float* __restrict__ Cout,
                                                   int M, int N, int K) {
    __shared__ uint16_t Al[2][128 * 32];
    __shared__ uint16_t Bl[2][128 * 32];
    const int lane = threadIdx.x & 63;
    const int w    = threadIdx.x >> 6;
    const int wr   = w >> 1, wc = w & 1;
    const int m0   = blockIdx.x * 128;
    const int n0   = blockIdx.y * 128;
    const int ql   = lane & 31;
    const int hi   = lane >> 5;

    const int srow = w * 32 + (lane >> 2);
    const int scol = (((lane & 3) ^ ((lane >> 2) & 3))) * 8;
    const uint16_t* Ag = A  + (size_t)(m0 + srow) * K + scol;
    const uint16_t* Bg = Bm + (size_t)(n0 + srow) * K + scol;
    const int loff = w * 32 * 32;
    const int qsw  = ql & 3;

    f32x16 acc[2][2] = {};
#pragma unroll
    for (int i = 0; i < 2; ++i) {
        gload_lds16(Ag + (size_t)i * 16 * K, &Al[0][loff + i * 16 * 32]);
        gload_lds16(Bg + (size_t)i * 16 * K, &Bl[0][loff + i * 16 * 32]);
    }

    int cur = 0;
    for (int k0 = 0; k0 < K; k0 += 32) {
        __syncthreads();
        if (k0 + 32 < K) {
            const int nb = cur ^ 1, k2 = k0 + 32;
#pragma unroll
            for (int i = 0; i < 2; ++i) {
                gload_lds16(Ag + (size_t)i * 16 * K + k2, &Al[nb][loff + i * 16 * 32]);
                gload_lds16(Bg + (size_t)i * 16 * K + k2, &Bl[nb][loff + i * 16 * 32]);
            }
        }
        s16x8 af[2][2], bfr[2][2];
#pragma unroll
        for (int am = 0; am < 2; ++am)
#pragma unroll
            for (int ks = 0; ks < 2; ++ks)
                af[am][ks] = *reinterpret_cast<const s16x8*>(
                    &Al[cur][(wr * 64 + am * 32 + ql) * 32 + (((ks * 2 + hi) ^ qsw) * 8)]);
#pragma unroll
        for (int bn = 0; bn < 2; ++bn)
#pragma unroll
            for (int ks = 0; ks < 2; ++ks)
                bfr[bn][ks] = *reinterpret_cast<const s16x8*>(
                    &Bl[cur][(wc * 64 + bn * 32 + ql) * 32 + (((ks * 2 + hi) ^ qsw) * 8)]);
#pragma unroll
        for (int am = 0; am < 2; ++am)
#pragma unroll
            for (int bn = 0; bn < 2; ++bn) {
                acc[am][bn] = __builtin_amdgcn_mfma_f32_32x32x16_bf16(af[am][0], bfr[bn][0],
                                                                      acc[am][bn], 0, 0, 0);
                acc[am][bn] = __builtin_amdgcn_mfma_f32_32x32x16_bf16(af[am][1], bfr[bn][1],
                                                                      acc[am][bn], 0, 0, 0);
            }
        cur ^= 1;
    }

#pragma unroll
    for (int am = 0; am < 2; ++am)
#pragma unroll
        for (int bn = 0; bn < 2; ++bn)
#pragma unroll
            for (int r = 0; r < 16; ++r) {
                const int cr = (r & 3) + 8 * (r >> 2);
                int row = m0 + wr * 64 + am * 32 + 4 * hi + cr;
                int col = n0 + wc * 64 + bn * 32 + ql;
                Cout[(size_t)row * N + col] = acc[am][bn][r];
            }
}

// ---------------- RoPE over contiguous q||k region, one pair/thread ----------------
__global__ __launch_bounds__(256) void rope_kernel(uint16_t* __restrict__ a,
                                                   const int* __restrict__ pos,
                                                   int npairs) {
    int t = blockIdx.x * 256 + threadIdx.x;
    if (t >= npairs) return;
    int j = t & 31;
    int s = (t >> 5) & (S_ - 1);
    float p   = (float)pos[s];
    float inv = exp2f(-(float)j * (13.287712379549449f / 32.0f));
    float ang = p * inv;
    float sn = __sinf(ang);
    float c  = __cosf(ang);
    uint32_t pr = *reinterpret_cast<uint32_t*>(a + (size_t)2 * t);
    float x0 = bf2f((uint16_t)(pr & 0xFFFF));
    float x1 = bf2f((uint16_t)(pr >> 16));
    float r0 = x0 * c - x1 * sn;
    float r1 = x0 * sn + x1 * c;
    uint32_t ot = (uint32_t)f2bf(r0) | ((uint32_t)f2bf(r1) << 16);
    *reinterpret_cast<uint32_t*>(a + (size_t)2 * t) = ot;
}

// ---------------- causal flash attention, 32x32 MFMA, shared-LDS K/V dbuf ----------
__global__ __launch_bounds__(256, 2) void flash_attn(const uint16_t* __restrict__ qg,
                                                     const uint16_t* __restrict__ kg,
                                                     const uint16_t* __restrict__ vtg,
                                                     uint16_t* __restrict__ attn) {
    __shared__ __align__(16) uint16_t Kl[2][4096];     // 2 x 64 keys x 64 dk (swizzled)
    __shared__ __align__(16) uint16_t Vl[2][4096];     // 2 x 64 dk x 64 keys (swizzled)
    const int lane = threadIdx.x & 63;
    const int w    = threadIdx.x >> 6;     // 0..3
    const int ql   = lane & 31;
    const int hi   = lane >> 5;
    const int id   = blockIdx.x;
    const int bh   = (id & 7) * 8 + ((id >> 3) & 7);   // 8 bh per XCD
    const int s    = 15 - (id >> 6);       // big supertiles dispatch first (LPT)
    const int b    = bh >> 4, hh = bh & 15;

    const uint16_t* kb_ = kg  + (size_t)bh * S_ * DK_;
    const uint16_t* vb_ = vtg + (size_t)bh * DK_ * S_;

    char* obb = (char*)&Kl[0][0] + w * 4096;   // per-wave 4KB, aliases Kl
    const int swz = (ql & 7) << 4;

    const int q0 = s * 128 + w * 32;
    const int rowg  = q0 + ql;
    const int ntmax = 2 * s + 2;           // block-uniform (barrier-safe)

    const int srow = lane >> 3;                       // 0..7
    const int scol = ((lane & 7) ^ srow) << 3;        // pre-swizzled source chunk

    const uint16_t* qp = qg + ((size_t)bh * S_ + q0 + ql) * DK_ + hi * 8;
    s16x8 qf[4];
#pragma unroll
    for (int kk = 0; kk < 4; ++kk)
        qf[kk] = *reinterpret_cast<const s16x8*>(qp + kk * 16);

    f32x16 o0 = {}, o1 = {};
    float l_l = 0.f;

    // prologue: stage tile 0 into buffer 0 (wave w covers rows w*16 .. w*16+15)
#pragma unroll
    for (int i = 0; i < 2; ++i) {
        gload_lds16(kb_ + (size_t)(w * 16 + i * 8 + srow) * DK_ + scol, &Kl[0][w * 1024 + i * 512]);
        gload_lds16(vb_ + (size_t)(w * 16 + i * 8 + srow) * S_  + scol, &Vl[0][w * 1024 + i * 512]);
    }

    for (int t = 0; t < ntmax; ++t) {
        const int kt  = t * 64;
        const int cur = t & 1;
        __syncthreads();
        if (t + 1 < ntmax) {
            const int kt2 = kt + 64, nb = cur ^ 1;
#pragma unroll
            for (int i = 0; i < 2; ++i) {
                gload_lds16(kb_ + (size_t)(kt2 + w * 16 + i * 8 + srow) * DK_ + scol,
                            &Kl[nb][w * 1024 + i * 512]);
                gload_lds16(vb_ + (size_t)(w * 16 + i * 8 + srow) * S_ + kt2 + scol,
                            &Vl[nb][w * 1024 + i * 512]);
            }
        }
        if (kt > q0 + 31) continue;        // fully-masked tile (wave-uniform)

        s16x8 kf[8];
#pragma unroll
        for (int kb2 = 0; kb2 < 2; ++kb2)
#pragma unroll
            for (int kk = 0; kk < 4; ++kk)
                kf[kb2 * 4 + kk] = *reinterpret_cast<const s16x8*>(
                    &Kl[cur][(kb2 * 32 + ql) * 64 + (((kk * 32 + hi * 16) ^ swz) >> 1)]);

        f32x16 sc0 = {}, sc1 = {};
        __builtin_amdgcn_s_setprio(1);
#pragma unroll
        for (int kk = 0; kk < 4; ++kk)
            sc0 = __builtin_amdgcn_mfma_f32_32x32x16_bf16(kf[kk], qf[kk], sc0, 0, 0, 0);
#pragma unroll
        for (int kk = 0; kk < 4; ++kk)
            sc1 = __builtin_amdgcn_mfma_f32_32x32x16_bf16(kf[4 + kk], qf[kk], sc1, 0, 0, 0);
        __builtin_amdgcn_s_setprio(0);

        // causal mask (scores already in log2 domain; Q pre-scaled)
        if (kt + 63 > q0) {
            const int keybase = kt + 4 * hi;
#pragma unroll
            for (int r = 0; r < 16; ++r) {
                const int cr = (r & 3) + 8 * (r >> 2);
                if (keybase + cr > rowg)      sc0[r] = -3e38f;
                if (keybase + cr + 32 > rowg) sc1[r] = -3e38f;
            }
        }

        // p = exp2(sc), lane-local sum
#pragma unroll
        for (int r = 0; r < 16; ++r) {
            float p0 = exp2f(sc0[r]);
            float p1 = exp2f(sc1[r]);
            sc0[r] = p0; sc1[r] = p1;
            l_l += p0 + p1;
        }

        // P -> bf16 B-fragments: cvt_pk + permlane32_swap
        s16x8 pf[4];
        {
            union PW { uint32_t u[4]; s16x8 v; };
#pragma unroll
            for (int half = 0; half < 2; ++half) {
                const f32x16& e = half ? sc1 : sc0;
#pragma unroll
                for (int sl = 0; sl < 2; ++sl) {
                    const int rb = sl * 8;
                    uint32_t a0 = cvt_pk_bf16(e[rb + 0], e[rb + 1]);
                    uint32_t b0 = cvt_pk_bf16(e[rb + 4], e[rb + 5]);
                    uint32_t a1 = cvt_pk_bf16(e[rb + 2], e[rb + 3]);
                    uint32_t b1 = cvt_pk_bf16(e[rb + 6], e[rb + 7]);
                    asm("v_permlane32_swap_b32 %0, %1" : "+v"(a0), "+v"(b0));
                    asm("v_permlane32_swap_b32 %0, %1" : "+v"(a1), "+v"(b1));
                    PW pw; pw.u[0] = a0; pw.u[1] = a1; pw.u[2] = b0; pw.u[3] = b1;
                    pf[half * 2 + sl] = pw.v;
                }
            }
        }

        s16x8 vf[8];
#pragma unroll
        for (int db = 0; db < 2; ++db)
#pragma unroll
            for (int ks = 0; ks < 4; ++ks)
                vf[db * 4 + ks] = *reinterpret_cast<const s16x8*>(
                    &Vl[cur][(db * 32 + ql) * 64 + (((ks * 32 + hi * 16) ^ swz) >> 1)]);

        __builtin_amdgcn_s_setprio(1);
#pragma unroll
        for (int ks = 0; ks < 4; ++ks) {
            o0 = __builtin_amdgcn_mfma_f32_32x32x16_bf16(vf[ks],     pf[ks], o0, 0, 0, 0);
            o1 = __builtin_amdgcn_mfma_f32_32x32x16_bf16(vf[4 + ks], pf[ks], o1, 0, 0, 0);
        }
        __builtin_amdgcn_s_setprio(0);
    }

    __syncthreads();   // all waves done with Kl before aliased epilogue writes

    // epilogue
    l_l += __shfl_xor(l_l, 32);
    float rinv = 1.0f / l_l;

#pragma unroll
    for (int db = 0; db < 2; ++db) {
        const f32x16& o = db ? o1 : o0;
#pragma unroll
        for (int rq = 0; rq < 4; ++rq) {
            uint2 val;
            val.x = cvt_pk_bf16(o[4 * rq + 0] * rinv, o[4 * rq + 1] * rinv);
            val.y = cvt_pk_bf16(o[4 * rq + 2] * rinv, o[4 * rq + 3] * rinv);
            int colb = (db * 32 + 8 * rq + 4 * hi) * 2;
            *reinterpret_cast<uint2*>(obb + ql * 128 + (colb ^ swz)) = val;
        }
    }
    uint16_t* orow = attn + ((size_t)b * S_ + q0 + ql) * DM_ + hh * 64 + hi * 32;
#pragma unroll
    for (int i = 0; i < 4; ++i) {
        int colb = hi * 64 + i * 16;
        s16x8 vrow = *reinterpret_cast<const s16x8*>(obb + ql * 128 + (colb ^ swz));
        *reinterpret_cast<s16x8*>(orow + i * 8) = vrow;
    }
}

extern "C" void kernel_launch(void* const* d_in, const int* in_sizes, int n_in,
                              void* d_out, int out_size, void* d_ws, size_t ws_size,
                              hipStream_t stream) {
    (void)in_sizes; (void)n_in; (void)out_size;
    const float* x   = (const float*)d_in[0];
    const float* wq  = (const float*)d_in[1];
    const float* wk  = (const float*)d_in[2];
    const float* wv  = (const float*)d_in[3];
    const float* wo  = (const float*)d_in[4];
    const int* tpos  = (const int*)d_in[5];
    float* out = (float*)d_out;

    const size_t NX = (size_t)M_ * DM_;   // 8388608
    const size_t NW = (size_t)DM_ * DM_;  // 1048576
    const size_t need = (NX + 4 * NW + 4 * NX) * sizeof(uint16_t);
    if (ws_size < need) return;

    uint16_t* ws  = (uint16_t*)d_ws;
    uint16_t* xb  = ws;
    uint16_t* wqb = xb + NX;
    uint16_t* wkb = wqb + NW;
    uint16_t* wvb = wkb + NW;
    uint16_t* wob = wvb + NW;
    uint16_t* qb  = wob + NW;
    uint16_t* kb  = qb + NX;    // contiguous with qb (rope covers both)
    uint16_t* vtb = kb + NX;
    uint16_t* ab  = vtb + NX;

    cvt_all<<<(int)((NX + 4 * NW) / 1024), 256, 0, stream>>>(x, wq, wk, wv, wo,
                                                             xb, wqb, wkb, wvb, wob);

    gemm_qkv<<<dim3(24, M_ / 128), 256, 0, stream>>>(xb, wqb, wkb, wvb, qb, kb, vtb);

    int npairs = 2 * B_ * H_ * S_ * (DK_ / 2);   // q and k together
    rope_kernel<<<npairs / 256, 256, 0, stream>>>(qb, tpos, npairs);

    flash_attn<<<dim3(1024), 256, 0, stream>>>(qb, kb, vtb, ab);

    gemm_out<<<dim3(M_ / 128, DM_ / 128), 256, 0, stream>>>(ab, wob, out, M_, DM_, DM_);
}

// Round 19
// 195.869 us; speedup vs baseline: 1.0339x; 1.0339x over previous
//
#include <hip/hip_runtime.h>
#include <stdint.h>

#define B_   4
#define S_   2048
#define H_   16
#define DK_  64
#define DM_  1024
#define M_   (B_ * S_)   // 8192

typedef __attribute__((ext_vector_type(4)))  float f32x4;
typedef __attribute__((ext_vector_type(16))) float f32x16;
typedef __attribute__((ext_vector_type(8)))  short s16x8;

#define SCQ 0.18033688011112042f   // (1/sqrt(64)) * log2(e), folded into Q

__device__ __forceinline__ uint16_t f2bf(float f) {
    union { float f; uint32_t u; } v; v.f = f;
    uint32_t u = v.u;
    uint32_t r = (u + 0x7FFFu + ((u >> 16) & 1u)) >> 16;  // RNE
    return (uint16_t)r;
}
__device__ __forceinline__ float bf2f(uint16_t h) {
    union { uint32_t u; float f; } v; v.u = ((uint32_t)h) << 16;
    return v.f;
}
__device__ __forceinline__ uint32_t cvt_pk_bf16(float lo, float hi) {
    uint32_t r;
    asm("v_cvt_pk_bf16_f32 %0, %1, %2" : "=v"(r) : "v"(lo), "v"(hi));
    return r;
}

// async global->LDS, 16B per lane; lds base must be wave-uniform
__device__ __forceinline__ void gload_lds16(const uint16_t* g, uint16_t* l) {
    __builtin_amdgcn_global_load_lds(
        (const __attribute__((address_space(1))) void*)g,
        (__attribute__((address_space(3))) void*)l, 16, 0, 0);
}

// ---------------- fp32 -> bf16 convert, ALL inputs in one launch ----------------
__global__ __launch_bounds__(256) void cvt_all(const float* __restrict__ x,
                                               const float* __restrict__ w0,
                                               const float* __restrict__ w1,
                                               const float* __restrict__ w2,
                                               const float* __restrict__ w3,
                                               uint16_t* __restrict__ xo,
                                               uint16_t* __restrict__ o0,
                                               uint16_t* __restrict__ o1,
                                               uint16_t* __restrict__ o2,
                                               uint16_t* __restrict__ o3) {
    const size_t NX = (size_t)M_ * DM_;
    const size_t NW = (size_t)DM_ * DM_;
    size_t i = ((size_t)blockIdx.x * 256 + threadIdx.x) * 4;
    const float* in; uint16_t* out; size_t off;
    if (i < NX) { in = x; out = xo; off = i; }
    else {
        size_t j = i - NX;
        int sel = (int)(j >> 20);
        off = j & (NW - 1);
        in  = sel == 0 ? w0 : sel == 1 ? w1 : sel == 2 ? w2 : w3;
        out = sel == 0 ? o0 : sel == 1 ? o1 : sel == 2 ? o2 : o3;
    }
    float4 v = *reinterpret_cast<const float4*>(in + off);
    ushort4 o;
    o.x = f2bf(v.x); o.y = f2bf(v.y); o.z = f2bf(v.z); o.w = f2bf(v.w);
    *reinterpret_cast<ushort4*>(out + off) = o;
}

// ---------------- fused QKV projection, dbuf, 32x32x16 MFMA ----------------
// Swizzle key (row>>1)&3: the 32-row fragment read groups lanes by row&1 (bank
// base 0/16); (row>>1)&3 cycles all 4 chunk slots within each parity group ->
// 4-way conflict (was 8-way with row&3 -> 18.9M conflict cycles in r18).
__global__ __launch_bounds__(256, 4) void gemm_qkv(const uint16_t* __restrict__ xb,
                                                   const uint16_t* __restrict__ wq,
                                                   const uint16_t* __restrict__ wk,
                                                   const uint16_t* __restrict__ wv,
                                                   uint16_t* __restrict__ qout,
                                                   uint16_t* __restrict__ kout,
                                                   uint16_t* __restrict__ vout) {
    __shared__ uint16_t Al[2][128 * 32];
    __shared__ uint16_t Bl[2][128 * 32];
    const int K = DM_;
    const int lane = threadIdx.x & 63;
    const int w    = threadIdx.x >> 6;
    const int wr   = w >> 1, wc = w & 1;
    const int sel  = blockIdx.x >> 3;
    const int np   = blockIdx.x & 7;
    const int y    = blockIdx.y;
    const int ql   = lane & 31;
    const int hi   = lane >> 5;

    const uint16_t* Aptr; const uint16_t* Bptr;
    int m0, n0;
    if (sel == 2) { Aptr = wv; Bptr = xb; m0 = np * 128; n0 = y * 128; }
    else          { Aptr = xb; Bptr = sel ? wk : wq; m0 = y * 128; n0 = np * 128; }

    const int srow = w * 32 + (lane >> 2);
    const int scol = (((lane & 3) ^ ((lane >> 3) & 3))) * 8;   // key=(row>>1)&3
    const uint16_t* Ag = Aptr + (size_t)(m0 + srow) * K + scol;
    const uint16_t* Bg = Bptr + (size_t)(n0 + srow) * K + scol;
    const int loff = w * 32 * 32;   // wave-uniform LDS base (elements)
    const int qsw  = (ql >> 1) & 3; // read-side XOR key ((ROW>>1)&3)

    f32x16 acc[2][2] = {};
    // prologue: stage K-step 0 into buffer 0
#pragma unroll
    for (int i = 0; i < 2; ++i) {
        gload_lds16(Ag + (size_t)i * 16 * K, &Al[0][loff + i * 16 * 32]);
        gload_lds16(Bg + (size_t)i * 16 * K, &Bl[0][loff + i * 16 * 32]);
    }

    int cur = 0;
    for (int k0 = 0; k0 < K; k0 += 32) {
        __syncthreads();   // drains vmcnt: buf[cur] landed; buf[cur^1] reads done
        if (k0 + 32 < K) {
            const int nb = cur ^ 1, k2 = k0 + 32;
#pragma unroll
            for (int i = 0; i < 2; ++i) {
                gload_lds16(Ag + (size_t)i * 16 * K + k2, &Al[nb][loff + i * 16 * 32]);
                gload_lds16(Bg + (size_t)i * 16 * K + k2, &Bl[nb][loff + i * 16 * 32]);
            }
        }
        s16x8 af[2][2], bfr[2][2];
#pragma unroll
        for (int am = 0; am < 2; ++am)
#pragma unroll
            for (int ks = 0; ks < 2; ++ks)
                af[am][ks] = *reinterpret_cast<const s16x8*>(
                    &Al[cur][(wr * 64 + am * 32 + ql) * 32 + (((ks * 2 + hi) ^ qsw) * 8)]);
#pragma unroll
        for (int bn = 0; bn < 2; ++bn)
#pragma unroll
            for (int ks = 0; ks < 2; ++ks)
                bfr[bn][ks] = *reinterpret_cast<const s16x8*>(
                    &Bl[cur][(wc * 64 + bn * 32 + ql) * 32 + (((ks * 2 + hi) ^ qsw) * 8)]);
#pragma unroll
        for (int am = 0; am < 2; ++am)
#pragma unroll
            for (int bn = 0; bn < 2; ++bn) {
                acc[am][bn] = __builtin_amdgcn_mfma_f32_32x32x16_bf16(af[am][0], bfr[bn][0],
                                                                      acc[am][bn], 0, 0, 0);
                acc[am][bn] = __builtin_amdgcn_mfma_f32_32x32x16_bf16(af[am][1], bfr[bn][1],
                                                                      acc[am][bn], 0, 0, 0);
            }
        cur ^= 1;
    }

#pragma unroll
    for (int am = 0; am < 2; ++am)
#pragma unroll
        for (int bn = 0; bn < 2; ++bn)
#pragma unroll
            for (int r = 0; r < 16; ++r) {
                const int cr = (r & 3) + 8 * (r >> 2);
                int row = m0 + wr * 64 + am * 32 + 4 * hi + cr;
                int col = n0 + wc * 64 + bn * 32 + ql;
                float v = acc[am][bn][r];
                if (sel == 2) {   // row over DM (h,dk), col over M (b,s)
                    int h = row >> 6,  dk = row & 63;
                    int b = col >> 11, s = col & (S_ - 1);
                    vout[(((size_t)(b * H_ + h)) * DK_ + dk) * S_ + s] = f2bf(v);
                } else {
                    int b = row >> 11, s = row & (S_ - 1);
                    int h = col >> 6,  dk = col & 63;
                    uint16_t bv = f2bf(sel ? v : v * SCQ);
                    (sel ? kout : qout)[(((size_t)(b * H_ + h)) * S_ + s) * DK_ + dk] = bv;
                }
            }
}

// ---------------- out-projection GEMM, dbuf, 32x32x16: C fp32 = attn * wo^T ----
__global__ __launch_bounds__(256, 4) void gemm_out(const uint16_t* __restrict__ A,
                                                   const uint16_t* __restrict__ Bm,
                                                   float* __restrict__ Cout,
                                                   int M, int N, int K) {
    __shared__ uint16_t Al[2][128 * 32];
    __shared__ uint16_t Bl[2][128 * 32];
    const int lane = threadIdx.x & 63;
    const int w    = threadIdx.x >> 6;
    const int wr   = w >> 1, wc = w & 1;
    const int m0   = blockIdx.x * 128;
    const int n0   = blockIdx.y * 128;
    const int ql   = lane & 31;
    const int hi   = lane >> 5;

    const int srow = w * 32 + (lane >> 2);
    const int scol = (((lane & 3) ^ ((lane >> 3) & 3))) * 8;
    const uint16_t* Ag = A  + (size_t)(m0 + srow) * K + scol;
    const uint16_t* Bg = Bm + (size_t)(n0 + srow) * K + scol;
    const int loff = w * 32 * 32;
    const int qsw  = (ql >> 1) & 3;

    f32x16 acc[2][2] = {};
#pragma unroll
    for (int i = 0; i < 2; ++i) {
        gload_lds16(Ag + (size_t)i * 16 * K, &Al[0][loff + i * 16 * 32]);
        gload_lds16(Bg + (size_t)i * 16 * K, &Bl[0][loff + i * 16 * 32]);
    }

    int cur = 0;
    for (int k0 = 0; k0 < K; k0 += 32) {
        __syncthreads();
        if (k0 + 32 < K) {
            const int nb = cur ^ 1, k2 = k0 + 32;
#pragma unroll
            for (int i = 0; i < 2; ++i) {
                gload_lds16(Ag + (size_t)i * 16 * K + k2, &Al[nb][loff + i * 16 * 32]);
                gload_lds16(Bg + (size_t)i * 16 * K + k2, &Bl[nb][loff + i * 16 * 32]);
            }
        }
        s16x8 af[2][2], bfr[2][2];
#pragma unroll
        for (int am = 0; am < 2; ++am)
#pragma unroll
            for (int ks = 0; ks < 2; ++ks)
                af[am][ks] = *reinterpret_cast<const s16x8*>(
                    &Al[cur][(wr * 64 + am * 32 + ql) * 32 + (((ks * 2 + hi) ^ qsw) * 8)]);
#pragma unroll
        for (int bn = 0; bn < 2; ++bn)
#pragma unroll
            for (int ks = 0; ks < 2; ++ks)
                bfr[bn][ks] = *reinterpret_cast<const s16x8*>(
                    &Bl[cur][(wc * 64 + bn * 32 + ql) * 32 + (((ks * 2 + hi) ^ qsw) * 8)]);
#pragma unroll
        for (int am = 0; am < 2; ++am)
#pragma unroll
            for (int bn = 0; bn < 2; ++bn) {
                acc[am][bn] = __builtin_amdgcn_mfma_f32_32x32x16_bf16(af[am][0], bfr[bn][0],
                                                                      acc[am][bn], 0, 0, 0);
                acc[am][bn] = __builtin_amdgcn_mfma_f32_32x32x16_bf16(af[am][1], bfr[bn][1],
                                                                      acc[am][bn], 0, 0, 0);
            }
        cur ^= 1;
    }

#pragma unroll
    for (int am = 0; am < 2; ++am)
#pragma unroll
        for (int bn = 0; bn < 2; ++bn)
#pragma unroll
            for (int r = 0; r < 16; ++r) {
                const int cr = (r & 3) + 8 * (r >> 2);
                int row = m0 + wr * 64 + am * 32 + 4 * hi + cr;
                int col = n0 + wc * 64 + bn * 32 + ql;
                Cout[(size_t)row * N + col] = acc[am][bn][r];
            }
}

// ---------------- RoPE over contiguous q||k region, one pair/thread ----------------
__global__ __launch_bounds__(256) void rope_kernel(uint16_t* __restrict__ a,
                                                   const int* __restrict__ pos,
                                                   int npairs) {
    int t = blockIdx.x * 256 + threadIdx.x;
    if (t >= npairs) return;
    int j = t & 31;
    int s = (t >> 5) & (S_ - 1);
    float p   = (float)pos[s];
    float inv = exp2f(-(float)j * (13.287712379549449f / 32.0f));
    float ang = p * inv;
    float sn = __sinf(ang);
    float c  = __cosf(ang);
    uint32_t pr = *reinterpret_cast<uint32_t*>(a + (size_t)2 * t);
    float x0 = bf2f((uint16_t)(pr & 0xFFFF));
    float x1 = bf2f((uint16_t)(pr >> 16));
    float r0 = x0 * c - x1 * sn;
    float r1 = x0 * sn + x1 * c;
    uint32_t ot = (uint32_t)f2bf(r0) | ((uint32_t)f2bf(r1) << 16);
    *reinterpret_cast<uint32_t*>(a + (size_t)2 * t) = ot;
}

// ---------------- causal flash attention, 32x32 MFMA, shared-LDS K/V dbuf ----------
__global__ __launch_bounds__(256, 2) void flash_attn(const uint16_t* __restrict__ qg,
                                                     const uint16_t* __restrict__ kg,
                                                     const uint16_t* __restrict__ vtg,
                                                     uint16_t* __restrict__ attn) {
    __shared__ __align__(16) uint16_t Kl[2][4096];     // 2 x 64 keys x 64 dk (swizzled)
    __shared__ __align__(16) uint16_t Vl[2][4096];     // 2 x 64 dk x 64 keys (swizzled)
    const int lane = threadIdx.x & 63;
    const int w    = threadIdx.x >> 6;     // 0..3
    const int ql   = lane & 31;
    const int hi   = lane >> 5;
    const int id   = blockIdx.x;
    const int bh   = (id & 7) * 8 + ((id >> 3) & 7);   // 8 bh per XCD
    const int s    = 15 - (id >> 6);       // big supertiles dispatch first (LPT)
    const int b    = bh >> 4, hh = bh & 15;

    const uint16_t* kb_ = kg  + (size_t)bh * S_ * DK_;
    const uint16_t* vb_ = vtg + (size_t)bh * DK_ * S_;

    char* obb = (char*)&Kl[0][0] + w * 4096;   // per-wave 4KB, aliases Kl
    const int swz = (ql & 7) << 4;

    const int q0 = s * 128 + w * 32;
    const int rowg  = q0 + ql;
    const int ntmax = 2 * s + 2;           // block-uniform (barrier-safe)

    const int srow = lane >> 3;                       // 0..7
    const int scol = ((lane & 7) ^ srow) << 3;        // pre-swizzled source chunk

    const uint16_t* qp = qg + ((size_t)bh * S_ + q0 + ql) * DK_ + hi * 8;
    s16x8 qf[4];
#pragma unroll
    for (int kk = 0; kk < 4; ++kk)
        qf[kk] = *reinterpret_cast<const s16x8*>(qp + kk * 16);

    f32x16 o0 = {}, o1 = {};
    float l_l = 0.f;

    // prologue: stage tile 0 into buffer 0 (wave w covers rows w*16 .. w*16+15)
#pragma unroll
    for (int i = 0; i < 2; ++i) {
        gload_lds16(kb_ + (size_t)(w * 16 + i * 8 + srow) * DK_ + scol, &Kl[0][w * 1024 + i * 512]);
        gload_lds16(vb_ + (size_t)(w * 16 + i * 8 + srow) * S_  + scol, &Vl[0][w * 1024 + i * 512]);
    }

    for (int t = 0; t < ntmax; ++t) {
        const int kt  = t * 64;
        const int cur = t & 1;
        __syncthreads();
        if (t + 1 < ntmax) {
            const int kt2 = kt + 64, nb = cur ^ 1;
#pragma unroll
            for (int i = 0; i < 2; ++i) {
                gload_lds16(kb_ + (size_t)(kt2 + w * 16 + i * 8 + srow) * DK_ + scol,
                            &Kl[nb][w * 1024 + i * 512]);
                gload_lds16(vb_ + (size_t)(w * 16 + i * 8 + srow) * S_ + kt2 + scol,
                            &Vl[nb][w * 1024 + i * 512]);
            }
        }
        if (kt > q0 + 31) continue;        // fully-masked tile (wave-uniform)

        s16x8 kf[8];
#pragma unroll
        for (int kb2 = 0; kb2 < 2; ++kb2)
#pragma unroll
            for (int kk = 0; kk < 4; ++kk)
                kf[kb2 * 4 + kk] = *reinterpret_cast<const s16x8*>(
                    &Kl[cur][(kb2 * 32 + ql) * 64 + (((kk * 32 + hi * 16) ^ swz) >> 1)]);

        f32x16 sc0 = {}, sc1 = {};
        __builtin_amdgcn_s_setprio(1);
#pragma unroll
        for (int kk = 0; kk < 4; ++kk)
            sc0 = __builtin_amdgcn_mfma_f32_32x32x16_bf16(kf[kk], qf[kk], sc0, 0, 0, 0);
#pragma unroll
        for (int kk = 0; kk < 4; ++kk)
            sc1 = __builtin_amdgcn_mfma_f32_32x32x16_bf16(kf[4 + kk], qf[kk], sc1, 0, 0, 0);
        __builtin_amdgcn_s_setprio(0);

        // causal mask (scores already in log2 domain; Q pre-scaled)
        if (kt + 63 > q0) {
            const int keybase = kt + 4 * hi;
#pragma unroll
            for (int r = 0; r < 16; ++r) {
                const int cr = (r & 3) + 8 * (r >> 2);
                if (keybase + cr > rowg)      sc0[r] = -3e38f;
                if (keybase + cr + 32 > rowg) sc1[r] = -3e38f;
            }
        }

        // p = exp2(sc), lane-local sum
#pragma unroll
        for (int r = 0; r < 16; ++r) {
            float p0 = exp2f(sc0[r]);
            float p1 = exp2f(sc1[r]);
            sc0[r] = p0; sc1[r] = p1;
            l_l += p0 + p1;
        }

        // P -> bf16 B-fragments: cvt_pk + permlane32_swap
        s16x8 pf[4];
        {
            union PW { uint32_t u[4]; s16x8 v; };
#pragma unroll
            for (int half = 0; half < 2; ++half) {
                const f32x16& e = half ? sc1 : sc0;
#pragma unroll
                for (int sl = 0; sl < 2; ++sl) {
                    const int rb = sl * 8;
                    uint32_t a0 = cvt_pk_bf16(e[rb + 0], e[rb + 1]);
                    uint32_t b0 = cvt_pk_bf16(e[rb + 4], e[rb + 5]);
                    uint32_t a1 = cvt_pk_bf16(e[rb + 2], e[rb + 3]);
                    uint32_t b1 = cvt_pk_bf16(e[rb + 6], e[rb + 7]);
                    asm("v_permlane32_swap_b32 %0, %1" : "+v"(a0), "+v"(b0));
                    asm("v_permlane32_swap_b32 %0, %1" : "+v"(a1), "+v"(b1));
                    PW pw; pw.u[0] = a0; pw.u[1] = a1; pw.u[2] = b0; pw.u[3] = b1;
                    pf[half * 2 + sl] = pw.v;
                }
            }
        }

        s16x8 vf[8];
#pragma unroll
        for (int db = 0; db < 2; ++db)
#pragma unroll
            for (int ks = 0; ks < 4; ++ks)
                vf[db * 4 + ks] = *reinterpret_cast<const s16x8*>(
                    &Vl[cur][(db * 32 + ql) * 64 + (((ks * 32 + hi * 16) ^ swz) >> 1)]);

        __builtin_amdgcn_s_setprio(1);
#pragma unroll
        for (int ks = 0; ks < 4; ++ks) {
            o0 = __builtin_amdgcn_mfma_f32_32x32x16_bf16(vf[ks],     pf[ks], o0, 0, 0, 0);
            o1 = __builtin_amdgcn_mfma_f32_32x32x16_bf16(vf[4 + ks], pf[ks], o1, 0, 0, 0);
        }
        __builtin_amdgcn_s_setprio(0);
    }

    __syncthreads();   // all waves done with Kl before aliased epilogue writes

    // epilogue
    l_l += __shfl_xor(l_l, 32);
    float rinv = 1.0f / l_l;

#pragma unroll
    for (int db = 0; db < 2; ++db) {
        const f32x16& o = db ? o1 : o0;
#pragma unroll
        for (int rq = 0; rq < 4; ++rq) {
            uint2 val;
            val.x = cvt_pk_bf16(o[4 * rq + 0] * rinv, o[4 * rq + 1] * rinv);
            val.y = cvt_pk_bf16(o[4 * rq + 2] * rinv, o[4 * rq + 3] * rinv);
            int colb = (db * 32 + 8 * rq + 4 * hi) * 2;
            *reinterpret_cast<uint2*>(obb + ql * 128 + (colb ^ swz)) = val;
        }
    }
    uint16_t* orow = attn + ((size_t)b * S_ + q0 + ql) * DM_ + hh * 64 + hi * 32;
#pragma unroll
    for (int i = 0; i < 4; ++i) {
        int colb = hi * 64 + i * 16;
        s16x8 vrow = *reinterpret_cast<const s16x8*>(obb + ql * 128 + (colb ^ swz));
        *reinterpret_cast<s16x8*>(orow + i * 8) = vrow;
    }
}

extern "C" void kernel_launch(void* const* d_in, const int* in_sizes, int n_in,
                              void* d_out, int out_size, void* d_ws, size_t ws_size,
                              hipStream_t stream) {
    (void)in_sizes; (void)n_in; (void)out_size;
    const float* x   = (const float*)d_in[0];
    const float* wq  = (const float*)d_in[1];
    const float* wk  = (const float*)d_in[2];
    const float* wv  = (const float*)d_in[3];
    const float* wo  = (const float*)d_in[4];
    const int* tpos  = (const int*)d_in[5];
    float* out = (float*)d_out;

    const size_t NX = (size_t)M_ * DM_;   // 8388608
    const size_t NW = (size_t)DM_ * DM_;  // 1048576
    const size_t need = (NX + 4 * NW + 4 * NX) * sizeof(uint16_t);
    if (ws_size < need) return;

    uint16_t* ws  = (uint16_t*)d_ws;
    uint16_t* xb  = ws;
    uint16_t* wqb = xb + NX;
    uint16_t* wkb = wqb + NW;
    uint16_t* wvb = wkb + NW;
    uint16_t* wob = wvb + NW;
    uint16_t* qb  = wob + NW;
    uint16_t* kb  = qb + NX;    // contiguous with qb (rope covers both)
    uint16_t* vtb = kb + NX;
    uint16_t* ab  = vtb + NX;

    cvt_all<<<(int)((NX + 4 * NW) / 1024), 256, 0, stream>>>(x, wq, wk, wv, wo,
                                                             xb, wqb, wkb, wvb, wob);

    gemm_qkv<<<dim3(24, M_ / 128), 256, 0, stream>>>(xb, wqb, wkb, wvb, qb, kb, vtb);

    int npairs = 2 * B_ * H_ * S_ * (DK_ / 2);   // q and k together
    rope_kernel<<<npairs / 256, 256, 0, stream>>>(qb, tpos, npairs);

    flash_attn<<<dim3(1024), 256, 0, stream>>>(qb, kb, vtb, ab);

    gemm_out<<<dim3(M_ / 128, DM_ / 128), 256, 0, stream>>>(ab, wob, out, M_, DM_, DM_);
}

// Round 20
// 192.502 us; speedup vs baseline: 1.0520x; 1.0175x over previous
//
#include <hip/hip_runtime.h>
#include <stdint.h>

#define B_   4
#define S_   2048
#define H_   16
#define DK_  64
#define DM_  1024
#define M_   (B_ * S_)   // 8192

typedef __attribute__((ext_vector_type(4)))  float f32x4;
typedef __attribute__((ext_vector_type(16))) float f32x16;
typedef __attribute__((ext_vector_type(8)))  short s16x8;

#define SCQ 0.18033688011112042f   // (1/sqrt(64)) * log2(e), folded into Q

__device__ __forceinline__ uint16_t f2bf(float f) {
    union { float f; uint32_t u; } v; v.f = f;
    uint32_t u = v.u;
    uint32_t r = (u + 0x7FFFu + ((u >> 16) & 1u)) >> 16;  // RNE
    return (uint16_t)r;
}
__device__ __forceinline__ float bf2f(uint16_t h) {
    union { uint32_t u; float f; } v; v.u = ((uint32_t)h) << 16;
    return v.f;
}
__device__ __forceinline__ uint32_t cvt_pk_bf16(float lo, float hi) {
    uint32_t r;
    asm("v_cvt_pk_bf16_f32 %0, %1, %2" : "=v"(r) : "v"(lo), "v"(hi));
    return r;
}

// async global->LDS, 16B per lane; lds base must be wave-uniform
__device__ __forceinline__ void gload_lds16(const uint16_t* g, uint16_t* l) {
    __builtin_amdgcn_global_load_lds(
        (const __attribute__((address_space(1))) void*)g,
        (__attribute__((address_space(3))) void*)l, 16, 0, 0);
}

// ---------------- fp32 -> bf16 convert, ALL inputs in one launch ----------------
__global__ __launch_bounds__(256) void cvt_all(const float* __restrict__ x,
                                               const float* __restrict__ w0,
                                               const float* __restrict__ w1,
                                               const float* __restrict__ w2,
                                               const float* __restrict__ w3,
                                               uint16_t* __restrict__ xo,
                                               uint16_t* __restrict__ o0,
                                               uint16_t* __restrict__ o1,
                                               uint16_t* __restrict__ o2,
                                               uint16_t* __restrict__ o3) {
    const size_t NX = (size_t)M_ * DM_;
    const size_t NW = (size_t)DM_ * DM_;
    size_t i = ((size_t)blockIdx.x * 256 + threadIdx.x) * 4;
    const float* in; uint16_t* out; size_t off;
    if (i < NX) { in = x; out = xo; off = i; }
    else {
        size_t j = i - NX;
        int sel = (int)(j >> 20);
        off = j & (NW - 1);
        in  = sel == 0 ? w0 : sel == 1 ? w1 : sel == 2 ? w2 : w3;
        out = sel == 0 ? o0 : sel == 1 ? o1 : sel == 2 ? o2 : o3;
    }
    float4 v = *reinterpret_cast<const float4*>(in + off);
    ushort4 o;
    o.x = f2bf(v.x); o.y = f2bf(v.y); o.z = f2bf(v.z); o.w = f2bf(v.w);
    *reinterpret_cast<ushort4*>(out + off) = o;
}

// ---------------- fused QKV projection, dbuf, 32x32x16 MFMA ----------------
__global__ __launch_bounds__(256, 4) void gemm_qkv(const uint16_t* __restrict__ xb,
                                                   const uint16_t* __restrict__ wq,
                                                   const uint16_t* __restrict__ wk,
                                                   const uint16_t* __restrict__ wv,
                                                   uint16_t* __restrict__ qout,
                                                   uint16_t* __restrict__ kout,
                                                   uint16_t* __restrict__ vout) {
    __shared__ uint16_t Al[2][128 * 32];
    __shared__ uint16_t Bl[2][128 * 32];
    const int K = DM_;
    const int lane = threadIdx.x & 63;
    const int w    = threadIdx.x >> 6;
    const int wr   = w >> 1, wc = w & 1;
    const int sel  = blockIdx.x >> 3;
    const int np   = blockIdx.x & 7;
    const int y    = blockIdx.y;
    const int ql   = lane & 31;
    const int hi   = lane >> 5;

    const uint16_t* Aptr; const uint16_t* Bptr;
    int m0, n0;
    if (sel == 2) { Aptr = wv; Bptr = xb; m0 = np * 128; n0 = y * 128; }
    else          { Aptr = xb; Bptr = sel ? wk : wq; m0 = y * 128; n0 = np * 128; }

    const int srow = w * 32 + (lane >> 2);
    const int scol = (((lane & 3) ^ ((lane >> 3) & 3))) * 8;   // key=(row>>1)&3
    const uint16_t* Ag = Aptr + (size_t)(m0 + srow) * K + scol;
    const uint16_t* Bg = Bptr + (size_t)(n0 + srow) * K + scol;
    const int loff = w * 32 * 32;   // wave-uniform LDS base (elements)
    const int qsw  = (ql >> 1) & 3; // read-side XOR key ((ROW>>1)&3)

    f32x16 acc[2][2] = {};
    // prologue: stage K-step 0 into buffer 0
#pragma unroll
    for (int i = 0; i < 2; ++i) {
        gload_lds16(Ag + (size_t)i * 16 * K, &Al[0][loff + i * 16 * 32]);
        gload_lds16(Bg + (size_t)i * 16 * K, &Bl[0][loff + i * 16 * 32]);
    }

    int cur = 0;
    for (int k0 = 0; k0 < K; k0 += 32) {
        __syncthreads();   // drains vmcnt: buf[cur] landed; buf[cur^1] reads done
        if (k0 + 32 < K) {
            const int nb = cur ^ 1, k2 = k0 + 32;
#pragma unroll
            for (int i = 0; i < 2; ++i) {
                gload_lds16(Ag + (size_t)i * 16 * K + k2, &Al[nb][loff + i * 16 * 32]);
                gload_lds16(Bg + (size_t)i * 16 * K + k2, &Bl[nb][loff + i * 16 * 32]);
            }
        }
        s16x8 af[2][2], bfr[2][2];
#pragma unroll
        for (int am = 0; am < 2; ++am)
#pragma unroll
            for (int ks = 0; ks < 2; ++ks)
                af[am][ks] = *reinterpret_cast<const s16x8*>(
                    &Al[cur][(wr * 64 + am * 32 + ql) * 32 + (((ks * 2 + hi) ^ qsw) * 8)]);
#pragma unroll
        for (int bn = 0; bn < 2; ++bn)
#pragma unroll
            for (int ks = 0; ks < 2; ++ks)
                bfr[bn][ks] = *reinterpret_cast<const s16x8*>(
                    &Bl[cur][(wc * 64 + bn * 32 + ql) * 32 + (((ks * 2 + hi) ^ qsw) * 8)]);
#pragma unroll
        for (int am = 0; am < 2; ++am)
#pragma unroll
            for (int bn = 0; bn < 2; ++bn) {
                acc[am][bn] = __builtin_amdgcn_mfma_f32_32x32x16_bf16(af[am][0], bfr[bn][0],
                                                                      acc[am][bn], 0, 0, 0);
                acc[am][bn] = __builtin_amdgcn_mfma_f32_32x32x16_bf16(af[am][1], bfr[bn][1],
                                                                      acc[am][bn], 0, 0, 0);
            }
        cur ^= 1;
    }

#pragma unroll
    for (int am = 0; am < 2; ++am)
#pragma unroll
        for (int bn = 0; bn < 2; ++bn)
#pragma unroll
            for (int r = 0; r < 16; ++r) {
                const int cr = (r & 3) + 8 * (r >> 2);
                int row = m0 + wr * 64 + am * 32 + 4 * hi + cr;
                int col = n0 + wc * 64 + bn * 32 + ql;
                float v = acc[am][bn][r];
                if (sel == 2) {   // row over DM (h,dk), col over M (b,s)
                    int h = row >> 6,  dk = row & 63;
                    int b = col >> 11, s = col & (S_ - 1);
                    vout[(((size_t)(b * H_ + h)) * DK_ + dk) * S_ + s] = f2bf(v);
                } else {
                    int b = row >> 11, s = row & (S_ - 1);
                    int h = col >> 6,  dk = col & 63;
                    uint16_t bv = f2bf(sel ? v : v * SCQ);
                    (sel ? kout : qout)[(((size_t)(b * H_ + h)) * S_ + s) * DK_ + dk] = bv;
                }
            }
}

// ---------------- out-projection GEMM, dbuf, 32x32x16: C fp32 = attn * wo^T ----
__global__ __launch_bounds__(256, 4) void gemm_out(const uint16_t* __restrict__ A,
                                                   const uint16_t* __restrict__ Bm,
                                                   float* __restrict__ Cout,
                                                   int M, int N, int K) {
    __shared__ uint16_t Al[2][128 * 32];
    __shared__ uint16_t Bl[2][128 * 32];
    const int lane = threadIdx.x & 63;
    const int w    = threadIdx.x >> 6;
    const int wr   = w >> 1, wc = w & 1;
    const int m0   = blockIdx.x * 128;
    const int n0   = blockIdx.y * 128;
    const int ql   = lane & 31;
    const int hi   = lane >> 5;

    const int srow = w * 32 + (lane >> 2);
    const int scol = (((lane & 3) ^ ((lane >> 3) & 3))) * 8;
    const uint16_t* Ag = A  + (size_t)(m0 + srow) * K + scol;
    const uint16_t* Bg = Bm + (size_t)(n0 + srow) * K + scol;
    const int loff = w * 32 * 32;
    const int qsw  = (ql >> 1) & 3;

    f32x16 acc[2][2] = {};
#pragma unroll
    for (int i = 0; i < 2; ++i) {
        gload_lds16(Ag + (size_t)i * 16 * K, &Al[0][loff + i * 16 * 32]);
        gload_lds16(Bg + (size_t)i * 16 * K, &Bl[0][loff + i * 16 * 32]);
    }

    int cur = 0;
    for (int k0 = 0; k0 < K; k0 += 32) {
        __syncthreads();
        if (k0 + 32 < K) {
            const int nb = cur ^ 1, k2 = k0 + 32;
#pragma unroll
            for (int i = 0; i < 2; ++i) {
                gload_lds16(Ag + (size_t)i * 16 * K + k2, &Al[nb][loff + i * 16 * 32]);
                gload_lds16(Bg + (size_t)i * 16 * K + k2, &Bl[nb][loff + i * 16 * 32]);
            }
        }
        s16x8 af[2][2], bfr[2][2];
#pragma unroll
        for (int am = 0; am < 2; ++am)
#pragma unroll
            for (int ks = 0; ks < 2; ++ks)
                af[am][ks] = *reinterpret_cast<const s16x8*>(
                    &Al[cur][(wr * 64 + am * 32 + ql) * 32 + (((ks * 2 + hi) ^ qsw) * 8)]);
#pragma unroll
        for (int bn = 0; bn < 2; ++bn)
#pragma unroll
            for (int ks = 0; ks < 2; ++ks)
                bfr[bn][ks] = *reinterpret_cast<const s16x8*>(
                    &Bl[cur][(wc * 64 + bn * 32 + ql) * 32 + (((ks * 2 + hi) ^ qsw) * 8)]);
#pragma unroll
        for (int am = 0; am < 2; ++am)
#pragma unroll
            for (int bn = 0; bn < 2; ++bn) {
                acc[am][bn] = __builtin_amdgcn_mfma_f32_32x32x16_bf16(af[am][0], bfr[bn][0],
                                                                      acc[am][bn], 0, 0, 0);
                acc[am][bn] = __builtin_amdgcn_mfma_f32_32x32x16_bf16(af[am][1], bfr[bn][1],
                                                                      acc[am][bn], 0, 0, 0);
            }
        cur ^= 1;
    }

#pragma unroll
    for (int am = 0; am < 2; ++am)
#pragma unroll
        for (int bn = 0; bn < 2; ++bn)
#pragma unroll
            for (int r = 0; r < 16; ++r) {
                const int cr = (r & 3) + 8 * (r >> 2);
                int row = m0 + wr * 64 + am * 32 + 4 * hi + cr;
                int col = n0 + wc * 64 + bn * 32 + ql;
                Cout[(size_t)row * N + col] = acc[am][bn][r];
            }
}

// ---------------- RoPE, K only (Q roped inside flash prologue) ----------------
__global__ __launch_bounds__(256) void rope_kernel(uint16_t* __restrict__ a,
                                                   const int* __restrict__ pos,
                                                   int npairs) {
    int t = blockIdx.x * 256 + threadIdx.x;
    if (t >= npairs) return;
    int j = t & 31;
    int s = (t >> 5) & (S_ - 1);
    float p   = (float)pos[s];
    float inv = exp2f(-(float)j * (13.287712379549449f / 32.0f));
    float ang = p * inv;
    float sn = __sinf(ang);
    float c  = __cosf(ang);
    uint32_t pr = *reinterpret_cast<uint32_t*>(a + (size_t)2 * t);
    float x0 = bf2f((uint16_t)(pr & 0xFFFF));
    float x1 = bf2f((uint16_t)(pr >> 16));
    float r0 = x0 * c - x1 * sn;
    float r1 = x0 * sn + x1 * c;
    uint32_t ot = (uint32_t)f2bf(r0) | ((uint32_t)f2bf(r1) << 16);
    *reinterpret_cast<uint32_t*>(a + (size_t)2 * t) = ot;
}

// ---------------- causal flash attention, 32x32 MFMA, shared-LDS K/V dbuf ----------
// Q-RoPE fused into the prologue (Q loaded exactly once per block; rotation
// commutes with the SCQ pre-scale). K is roped by rope_kernel (K tiles are read
// 16x per bh -- in-flash K-rope would recompute 16x).
__global__ __launch_bounds__(256, 2) void flash_attn(const uint16_t* __restrict__ qg,
                                                     const uint16_t* __restrict__ kg,
                                                     const uint16_t* __restrict__ vtg,
                                                     const int* __restrict__ tpos,
                                                     uint16_t* __restrict__ attn) {
    __shared__ __align__(16) uint16_t Kl[2][4096];     // 2 x 64 keys x 64 dk (swizzled)
    __shared__ __align__(16) uint16_t Vl[2][4096];     // 2 x 64 dk x 64 keys (swizzled)
    const int lane = threadIdx.x & 63;
    const int w    = threadIdx.x >> 6;     // 0..3
    const int ql   = lane & 31;
    const int hi   = lane >> 5;
    const int id   = blockIdx.x;
    const int bh   = (id & 7) * 8 + ((id >> 3) & 7);   // 8 bh per XCD
    const int s    = 15 - (id >> 6);       // big supertiles dispatch first (LPT)
    const int b    = bh >> 4, hh = bh & 15;

    const uint16_t* kb_ = kg  + (size_t)bh * S_ * DK_;
    const uint16_t* vb_ = vtg + (size_t)bh * DK_ * S_;

    char* obb = (char*)&Kl[0][0] + w * 4096;   // per-wave 4KB, aliases Kl
    const int swz = (ql & 7) << 4;

    const int q0 = s * 128 + w * 32;
    const int rowg  = q0 + ql;
    const int ntmax = 2 * s + 2;           // block-uniform (barrier-safe)

    const int srow = lane >> 3;                       // 0..7
    const int scol = ((lane & 7) ^ srow) << 3;        // pre-swizzled source chunk

    // Q load + fused RoPE: lane holds row q0+ql, dk = kk*16 + hi*8 + [0..8)
    const uint16_t* qp = qg + ((size_t)bh * S_ + q0 + ql) * DK_ + hi * 8;
    const float prow = (float)tpos[rowg];
    const float FR = 13.287712379549449f / 32.0f;     // log2(10000)/32
    s16x8 qf[4];
#pragma unroll
    for (int kk = 0; kk < 4; ++kk) {
        s16x8 raw = *reinterpret_cast<const s16x8*>(qp + kk * 16);
        union { uint32_t u[4]; s16x8 v; } pw;
#pragma unroll
        for (int jj = 0; jj < 4; ++jj) {
            float x0 = bf2f((uint16_t)raw[2 * jj]);
            float x1 = bf2f((uint16_t)raw[2 * jj + 1]);
            float ang = prow * exp2f(-(float)(kk * 8 + hi * 4 + jj) * FR);
            float sn = __sinf(ang), cs = __cosf(ang);
            pw.u[jj] = cvt_pk_bf16(x0 * cs - x1 * sn, x0 * sn + x1 * cs);
        }
        qf[kk] = pw.v;
    }

    f32x16 o0 = {}, o1 = {};
    float l_l = 0.f;

    // prologue: stage tile 0 into buffer 0 (wave w covers rows w*16 .. w*16+15)
#pragma unroll
    for (int i = 0; i < 2; ++i) {
        gload_lds16(kb_ + (size_t)(w * 16 + i * 8 + srow) * DK_ + scol, &Kl[0][w * 1024 + i * 512]);
        gload_lds16(vb_ + (size_t)(w * 16 + i * 8 + srow) * S_  + scol, &Vl[0][w * 1024 + i * 512]);
    }

    for (int t = 0; t < ntmax; ++t) {
        const int kt  = t * 64;
        const int cur = t & 1;
        __syncthreads();
        if (t + 1 < ntmax) {
            const int kt2 = kt + 64, nb = cur ^ 1;
#pragma unroll
            for (int i = 0; i < 2; ++i) {
                gload_lds16(kb_ + (size_t)(kt2 + w * 16 + i * 8 + srow) * DK_ + scol,
                            &Kl[nb][w * 1024 + i * 512]);
                gload_lds16(vb_ + (size_t)(w * 16 + i * 8 + srow) * S_ + kt2 + scol,
                            &Vl[nb][w * 1024 + i * 512]);
            }
        }
        if (kt > q0 + 31) continue;        // fully-masked tile (wave-uniform)

        s16x8 kf[8];
#pragma unroll
        for (int kb2 = 0; kb2 < 2; ++kb2)
#pragma unroll
            for (int kk = 0; kk < 4; ++kk)
                kf[kb2 * 4 + kk] = *reinterpret_cast<const s16x8*>(
                    &Kl[cur][(kb2 * 32 + ql) * 64 + (((kk * 32 + hi * 16) ^ swz) >> 1)]);

        f32x16 sc0 = {}, sc1 = {};
        __builtin_amdgcn_s_setprio(1);
#pragma unroll
        for (int kk = 0; kk < 4; ++kk)
            sc0 = __builtin_amdgcn_mfma_f32_32x32x16_bf16(kf[kk], qf[kk], sc0, 0, 0, 0);
#pragma unroll
        for (int kk = 0; kk < 4; ++kk)
            sc1 = __builtin_amdgcn_mfma_f32_32x32x16_bf16(kf[4 + kk], qf[kk], sc1, 0, 0, 0);
        __builtin_amdgcn_s_setprio(0);

        // causal mask (scores already in log2 domain; Q pre-scaled)
        if (kt + 63 > q0) {
            const int keybase = kt + 4 * hi;
#pragma unroll
            for (int r = 0; r < 16; ++r) {
                const int cr = (r & 3) + 8 * (r >> 2);
                if (keybase + cr > rowg)      sc0[r] = -3e38f;
                if (keybase + cr + 32 > rowg) sc1[r] = -3e38f;
            }
        }

        // p = exp2(sc), lane-local sum
#pragma unroll
        for (int r = 0; r < 16; ++r) {
            float p0 = exp2f(sc0[r]);
            float p1 = exp2f(sc1[r]);
            sc0[r] = p0; sc1[r] = p1;
            l_l += p0 + p1;
        }

        // P -> bf16 B-fragments: cvt_pk + permlane32_swap
        s16x8 pf[4];
        {
            union PW { uint32_t u[4]; s16x8 v; };
#pragma unroll
            for (int half = 0; half < 2; ++half) {
                const f32x16& e = half ? sc1 : sc0;
#pragma unroll
                for (int sl = 0; sl < 2; ++sl) {
                    const int rb = sl * 8;
                    uint32_t a0 = cvt_pk_bf16(e[rb + 0], e[rb + 1]);
                    uint32_t b0 = cvt_pk_bf16(e[rb + 4], e[rb + 5]);
                    uint32_t a1 = cvt_pk_bf16(e[rb + 2], e[rb + 3]);
                    uint32_t b1 = cvt_pk_bf16(e[rb + 6], e[rb + 7]);
                    asm("v_permlane32_swap_b32 %0, %1" : "+v"(a0), "+v"(b0));
                    asm("v_permlane32_swap_b32 %0, %1" : "+v"(a1), "+v"(b1));
                    PW pw; pw.u[0] = a0; pw.u[1] = a1; pw.u[2] = b0; pw.u[3] = b1;
                    pf[half * 2 + sl] = pw.v;
                }
            }
        }

        s16x8 vf[8];
#pragma unroll
        for (int db = 0; db < 2; ++db)
#pragma unroll
            for (int ks = 0; ks < 4; ++ks)
                vf[db * 4 + ks] = *reinterpret_cast<const s16x8*>(
                    &Vl[cur][(db * 32 + ql) * 64 + (((ks * 32 + hi * 16) ^ swz) >> 1)]);

        __builtin_amdgcn_s_setprio(1);
#pragma unroll
        for (int ks = 0; ks < 4; ++ks) {
            o0 = __builtin_amdgcn_mfma_f32_32x32x16_bf16(vf[ks],     pf[ks], o0, 0, 0, 0);
            o1 = __builtin_amdgcn_mfma_f32_32x32x16_bf16(vf[4 + ks], pf[ks], o1, 0, 0, 0);
        }
        __builtin_amdgcn_s_setprio(0);
    }

    __syncthreads();   // all waves done with Kl before aliased epilogue writes

    // epilogue
    l_l += __shfl_xor(l_l, 32);
    float rinv = 1.0f / l_l;

#pragma unroll
    for (int db = 0; db < 2; ++db) {
        const f32x16& o = db ? o1 : o0;
#pragma unroll
        for (int rq = 0; rq < 4; ++rq) {
            uint2 val;
            val.x = cvt_pk_bf16(o[4 * rq + 0] * rinv, o[4 * rq + 1] * rinv);
            val.y = cvt_pk_bf16(o[4 * rq + 2] * rinv, o[4 * rq + 3] * rinv);
            int colb = (db * 32 + 8 * rq + 4 * hi) * 2;
            *reinterpret_cast<uint2*>(obb + ql * 128 + (colb ^ swz)) = val;
        }
    }
    uint16_t* orow = attn + ((size_t)b * S_ + q0 + ql) * DM_ + hh * 64 + hi * 32;
#pragma unroll
    for (int i = 0; i < 4; ++i) {
        int colb = hi * 64 + i * 16;
        s16x8 vrow = *reinterpret_cast<const s16x8*>(obb + ql * 128 + (colb ^ swz));
        *reinterpret_cast<s16x8*>(orow + i * 8) = vrow;
    }
}

extern "C" void kernel_launch(void* const* d_in, const int* in_sizes, int n_in,
                              void* d_out, int out_size, void* d_ws, size_t ws_size,
                              hipStream_t stream) {
    (void)in_sizes; (void)n_in; (void)out_size;
    const float* x   = (const float*)d_in[0];
    const float* wq  = (const float*)d_in[1];
    const float* wk  = (const float*)d_in[2];
    const float* wv  = (const float*)d_in[3];
    const float* wo  = (const float*)d_in[4];
    const int* tpos  = (const int*)d_in[5];
    float* out = (float*)d_out;

    const size_t NX = (size_t)M_ * DM_;   // 8388608
    const size_t NW = (size_t)DM_ * DM_;  // 1048576
    const size_t need = (NX + 4 * NW + 4 * NX) * sizeof(uint16_t);
    if (ws_size < need) return;

    uint16_t* ws  = (uint16_t*)d_ws;
    uint16_t* xb  = ws;
    uint16_t* wqb = xb + NX;
    uint16_t* wkb = wqb + NW;
    uint16_t* wvb = wkb + NW;
    uint16_t* wob = wvb + NW;
    uint16_t* qb  = wob + NW;
    uint16_t* kb  = qb + NX;
    uint16_t* vtb = kb + NX;
    uint16_t* ab  = vtb + NX;

    cvt_all<<<(int)((NX + 4 * NW) / 1024), 256, 0, stream>>>(x, wq, wk, wv, wo,
                                                             xb, wqb, wkb, wvb, wob);

    gemm_qkv<<<dim3(24, M_ / 128), 256, 0, stream>>>(xb, wqb, wkb, wvb, qb, kb, vtb);

    int npairs_k = B_ * H_ * S_ * (DK_ / 2);   // K only; Q roped inside flash
    rope_kernel<<<npairs_k / 256, 256, 0, stream>>>(kb, tpos, npairs_k);

    flash_attn<<<dim3(1024), 256, 0, stream>>>(qb, kb, vtb, tpos, ab);

    gemm_out<<<dim3(M_ / 128, DM_ / 128), 256, 0, stream>>>(ab, wob, out, M_, DM_, DM_);
}